// Round 1
// baseline (2042.347 us; speedup 1.0000x reference)
//
#include <hip/hip_runtime.h>
#include <math.h>

#define CH   64
#define KT   343
#define HIDD 256

// ---------------- Kernel A: depthwise gather conv + GroupNorm ----------------
// One wave (64 lanes) per voxel; lane = channel. 4 voxels per 256-thread block.
__global__ __launch_bounds__(256) void dw_gn_kernel(
    const float* __restrict__ x, const int* __restrict__ nbr,
    const float* __restrict__ W1, const float* __restrict__ b1,
    const float* __restrict__ gamma, const float* __restrict__ beta,
    float* __restrict__ hout, int N) {
  const int wave = threadIdx.x >> 6;
  const int lane = threadIdx.x & 63;
  const int i = blockIdx.x * 4 + wave;
  if (i >= N) return;

  const long base = (long)i * KT;
  float acc = 0.f;
  for (int k = 0; k < KT; ++k) {
    // neighbor index is wave-uniform -> force SGPR so the skip is a scalar branch
    int idx = __builtin_amdgcn_readfirstlane(nbr[base + k]);
    if (idx < N) {
      acc += x[(long)idx * CH + lane] * W1[k * CH + lane];
    }
  }
  acc += b1[lane];

  // GroupNorm over 64 channels == wave-wide reduction
  float s = acc, ss = acc * acc;
#pragma unroll
  for (int off = 32; off > 0; off >>= 1) {
    s  += __shfl_xor(s,  off);
    ss += __shfl_xor(ss, off);
  }
  const float mu  = s * (1.0f / 64.0f);
  const float var = ss * (1.0f / 64.0f) - mu * mu;
  const float inv = rsqrtf(var + 1e-5f);
  hout[(long)i * CH + lane] = (acc - mu) * inv * gamma[lane] + beta[lane];
}

// ---------------- Kernel B: MLP (64->256, exact GELU, 256->64) + residual ----
// 32 voxels per 256-thread block.
__global__ __launch_bounds__(256) void mlp_kernel(
    const float* __restrict__ h, const float* __restrict__ x,
    const float* __restrict__ W2, const float* __restrict__ b2,
    const float* __restrict__ W3, const float* __restrict__ b3,
    float* __restrict__ out, int N) {
  __shared__ float hs[32][CH];     // 8 KB
  __shared__ float gh[32][HIDD];   // 32 KB
  const int t = threadIdx.x;
  const long vbase = (long)blockIdx.x * 32;

  // cooperative load of the h tile (coalesced)
#pragma unroll
  for (int r = 0; r < 8; ++r) {
    int e = r * 256 + t;
    ((float*)hs)[e] = h[vbase * CH + e];
  }
  __syncthreads();

  // stage 1: thread t owns hidden unit j=t for all 32 voxels
  float w[CH];
#pragma unroll
  for (int c = 0; c < CH; ++c) w[c] = W2[c * HIDD + t];
  const float bb = b2[t];

  float acc[32];
  for (int v = 0; v < 32; ++v) {
    float a = 0.f;
#pragma unroll
    for (int c = 0; c < CH; ++c) a += hs[v][c] * w[c];  // LDS broadcast reads
    acc[v] = a + bb;
  }

  // exact GELU, stage into LDS
#pragma unroll
  for (int v = 0; v < 32; ++v) {
    float z = acc[v];
    gh[v][t] = 0.5f * z * (1.0f + erff(z * 0.70710678118654752f));
  }
  __syncthreads();

  // stage 2: lane c = t&63 produces out channel c; group vg = t>>6 covers 8 voxels
  const int c = t & 63, vg = t >> 6;
  float o[8];
#pragma unroll
  for (int vv = 0; vv < 8; ++vv) o[vv] = b3[c];
  for (int j = 0; j < HIDD; ++j) {
    float w3 = W3[j * CH + c];   // coalesced, L1-resident
#pragma unroll
    for (int vv = 0; vv < 8; ++vv) o[vv] += gh[vg * 8 + vv][j] * w3;  // broadcast
  }
#pragma unroll
  for (int vv = 0; vv < 8; ++vv) {
    long v = vbase + vg * 8 + vv;
    if (v < N) out[v * CH + c] = o[vv] + x[v * CH + c];
  }
}

extern "C" void kernel_launch(void* const* d_in, const int* in_sizes, int n_in,
                              void* d_out, int out_size, void* d_ws, size_t ws_size,
                              hipStream_t stream) {
  const float* x_feat = (const float*)d_in[0];
  const int*   nbr    = (const int*)d_in[1];
  const float* W1     = (const float*)d_in[2];
  const float* b1     = (const float*)d_in[3];
  const float* gamma  = (const float*)d_in[4];
  const float* beta   = (const float*)d_in[5];
  const float* W2     = (const float*)d_in[6];
  const float* b2     = (const float*)d_in[7];
  const float* W3     = (const float*)d_in[8];
  const float* b3     = (const float*)d_in[9];
  float* out = (float*)d_out;

  const int N = in_sizes[0] / CH;      // 100000
  float* hbuf = (float*)d_ws;          // [N, CH] fp32 = 25.6 MB

  dim3 blkA(256);
  dim3 grdA((N + 3) / 4);
  hipLaunchKernelGGL(dw_gn_kernel, grdA, blkA, 0, stream,
                     x_feat, nbr, W1, b1, gamma, beta, hbuf, N);

  dim3 blkB(256);
  dim3 grdB((N + 31) / 32);
  hipLaunchKernelGGL(mlp_kernel, grdB, blkB, 0, stream,
                     hbuf, x_feat, W2, b2, W3, b3, out, N);
}

// Round 2
// 737.631 us; speedup vs baseline: 2.7688x; 2.7688x over previous
//
#include <hip/hip_runtime.h>
#include <math.h>

#define CH    64
#define KT    343
#define HIDD  256
#define CHUNK 16

// ---------------- Kernel A: depthwise gather conv + GroupNorm ----------------
// One wave (64 lanes) per voxel; lane = channel. 4 voxels per 256-thread block.
// Two-phase chunked inner loop: batch-issue gathers, then batch FMAs, so the
// wave keeps many loads in flight instead of one serial latency per tap.
__global__ __launch_bounds__(256) void dw_gn_kernel(
    const float* __restrict__ x, const int* __restrict__ nbr,
    const float* __restrict__ W1, const float* __restrict__ b1,
    const float* __restrict__ gamma, const float* __restrict__ beta,
    float* __restrict__ hout, int N) {
  const int wave = threadIdx.x >> 6;
  const int lane = threadIdx.x & 63;
  const int i = blockIdx.x * 4 + wave;
  if (i >= N) return;

  const int* nb = nbr + (size_t)i * KT;
  const int sub = lane & (CHUNK - 1);
  float acc = 0.f;

  for (int k = 0; k < KT; k += CHUNK) {
    // one coalesced load grabs CHUNK neighbor indices (lanes repeat every 16)
    const int kk = k + sub;
    const int myidx = (kk < KT) ? nb[kk] : N;

    float g[CHUNK];   // gathered features (0 when tap invalid)
    float w[CHUNK];   // weights          (0 when tap invalid)
    // phase 1: broadcast idx to SGPR via readlane; issue all valid loads with
    // no intervening waits (scalar branch depends only on resident SGPRs)
#pragma unroll
    for (int j = 0; j < CHUNK; ++j) {
      const int idx = __builtin_amdgcn_readlane(myidx, j);
      if (idx < N) {
        g[j] = x[(size_t)idx * CH + lane];
        w[j] = W1[(size_t)(k + j) * CH + lane];
      } else {
        g[j] = 0.f;
        w[j] = 0.f;
      }
    }
    // phase 2: consume (waits drain here, overlapped across 16 loads)
#pragma unroll
    for (int j = 0; j < CHUNK; ++j) {
      acc = fmaf(g[j], w[j], acc);
    }
  }
  acc += b1[lane];

  // GroupNorm over 64 channels == wave-wide butterfly reduction
  float s = acc, ss = acc * acc;
#pragma unroll
  for (int off = 32; off > 0; off >>= 1) {
    s  += __shfl_xor(s,  off);
    ss += __shfl_xor(ss, off);
  }
  const float mu  = s * (1.0f / 64.0f);
  const float var = ss * (1.0f / 64.0f) - mu * mu;
  const float inv = rsqrtf(var + 1e-5f);
  hout[(size_t)i * CH + lane] = (acc - mu) * inv * gamma[lane] + beta[lane];
}

// ---------------- Kernel B: MLP (64->256, exact GELU, 256->64) + residual ----
// 32 voxels per 256-thread block. (unchanged this round)
__global__ __launch_bounds__(256) void mlp_kernel(
    const float* __restrict__ h, const float* __restrict__ x,
    const float* __restrict__ W2, const float* __restrict__ b2,
    const float* __restrict__ W3, const float* __restrict__ b3,
    float* __restrict__ out, int N) {
  __shared__ float hs[32][CH];     // 8 KB
  __shared__ float gh[32][HIDD];   // 32 KB
  const int t = threadIdx.x;
  const long vbase = (long)blockIdx.x * 32;

  // cooperative load of the h tile (coalesced)
#pragma unroll
  for (int r = 0; r < 8; ++r) {
    int e = r * 256 + t;
    ((float*)hs)[e] = h[vbase * CH + e];
  }
  __syncthreads();

  // stage 1: thread t owns hidden unit j=t for all 32 voxels
  float w[CH];
#pragma unroll
  for (int c = 0; c < CH; ++c) w[c] = W2[c * HIDD + t];
  const float bb = b2[t];

  float acc[32];
  for (int v = 0; v < 32; ++v) {
    float a = 0.f;
#pragma unroll
    for (int c = 0; c < CH; ++c) a += hs[v][c] * w[c];  // LDS broadcast reads
    acc[v] = a + bb;
  }

  // exact GELU, stage into LDS
#pragma unroll
  for (int v = 0; v < 32; ++v) {
    float z = acc[v];
    gh[v][t] = 0.5f * z * (1.0f + erff(z * 0.70710678118654752f));
  }
  __syncthreads();

  // stage 2: lane c = t&63 produces out channel c; group vg = t>>6 covers 8 voxels
  const int c = t & 63, vg = t >> 6;
  float o[8];
#pragma unroll
  for (int vv = 0; vv < 8; ++vv) o[vv] = b3[c];
  for (int j = 0; j < HIDD; ++j) {
    float w3 = W3[j * CH + c];   // coalesced, L1-resident
#pragma unroll
    for (int vv = 0; vv < 8; ++vv) o[vv] += gh[vg * 8 + vv][j] * w3;  // broadcast
  }
#pragma unroll
  for (int vv = 0; vv < 8; ++vv) {
    long v = vbase + vg * 8 + vv;
    if (v < N) out[v * CH + c] = o[vv] + x[v * CH + c];
  }
}

extern "C" void kernel_launch(void* const* d_in, const int* in_sizes, int n_in,
                              void* d_out, int out_size, void* d_ws, size_t ws_size,
                              hipStream_t stream) {
  const float* x_feat = (const float*)d_in[0];
  const int*   nbr    = (const int*)d_in[1];
  const float* W1     = (const float*)d_in[2];
  const float* b1     = (const float*)d_in[3];
  const float* gamma  = (const float*)d_in[4];
  const float* beta   = (const float*)d_in[5];
  const float* W2     = (const float*)d_in[6];
  const float* b2     = (const float*)d_in[7];
  const float* W3     = (const float*)d_in[8];
  const float* b3     = (const float*)d_in[9];
  float* out = (float*)d_out;

  const int N = in_sizes[0] / CH;      // 100000
  float* hbuf = (float*)d_ws;          // [N, CH] fp32 = 25.6 MB

  dim3 blkA(256);
  dim3 grdA((N + 3) / 4);
  hipLaunchKernelGGL(dw_gn_kernel, grdA, blkA, 0, stream,
                     x_feat, nbr, W1, b1, gamma, beta, hbuf, N);

  dim3 blkB(256);
  dim3 grdB((N + 31) / 32);
  hipLaunchKernelGGL(mlp_kernel, grdB, blkB, 0, stream,
                     hbuf, x_feat, W2, b2, W3, b3, out, N);
}

// Round 4
// 718.950 us; speedup vs baseline: 2.8407x; 1.0260x over previous
//
#include <hip/hip_runtime.h>
#include <math.h>

#define CH    64
#define KT    343
#define HIDD  256

// ---------------- Kernel A: depthwise gather conv + GroupNorm ----------------
// One wave per voxel; lane = channel. Voxel id is forced uniform via
// readfirstlane so the neighbor-table pointer is compiler-provably uniform:
// index loads become s_load (SGPR), the valid-tap branch is scalar, and
// gathers are saddr-form global_load_dword with a constant lane*4 vaddr.
__global__ __launch_bounds__(256) void dw_gn_kernel(
    const float* __restrict__ x, const int* __restrict__ nbr,
    const float* __restrict__ W1, const float* __restrict__ b1,
    const float* __restrict__ gamma, const float* __restrict__ beta,
    float* __restrict__ hout, int N) {
  const int lane = threadIdx.x & 63;
  // wave-uniform by construction; readfirstlane makes it provably uniform
  const int i = __builtin_amdgcn_readfirstlane(blockIdx.x * 4 + (threadIdx.x >> 6));
  if (i >= N) return;

  const int* nb = nbr + (size_t)i * KT;   // uniform pointer -> SGPR base
  float acc = 0.f;

  // 21 chunks of 16 -> taps 0..335
  for (int k = 0; k < 336; k += 16) {
    int idx[16];
    // phase 0: scalar index loads (compiler merges into s_load_dwordx4+)
#pragma unroll
    for (int j = 0; j < 16; ++j) idx[j] = nb[k + j];

    float g[16], w[16];
    const float* wb = W1 + k * CH;
    // phase 1: issue all valid gathers + weight loads, no intervening waits
#pragma unroll
    for (int j = 0; j < 16; ++j) {
      if (idx[j] < N) {                    // scalar branch (idx is SGPR)
        const float* p = x + ((size_t)(unsigned)idx[j] << 6);  // scalar base
        g[j] = p[lane];                    // saddr gather
        w[j] = wb[j * CH + lane];          // SGPR base + imm offset
      } else {
        g[j] = 0.f;
        w[j] = 0.f;
      }
    }
    // phase 2: consume (waits overlap across all in-flight loads)
#pragma unroll
    for (int j = 0; j < 16; ++j) acc = fmaf(g[j], w[j], acc);
  }

  // tail: taps 336..342
  {
    int idx[7];
#pragma unroll
    for (int j = 0; j < 7; ++j) idx[j] = nb[336 + j];
    float g[7], w[7];
    const float* wb = W1 + 336 * CH;
#pragma unroll
    for (int j = 0; j < 7; ++j) {
      if (idx[j] < N) {
        const float* p = x + ((size_t)(unsigned)idx[j] << 6);
        g[j] = p[lane];
        w[j] = wb[j * CH + lane];
      } else {
        g[j] = 0.f;
        w[j] = 0.f;
      }
    }
#pragma unroll
    for (int j = 0; j < 7; ++j) acc = fmaf(g[j], w[j], acc);
  }

  acc += b1[lane];

  // GroupNorm over 64 channels == wave-wide butterfly reduction
  float s = acc, ss = acc * acc;
#pragma unroll
  for (int off = 32; off > 0; off >>= 1) {
    s  += __shfl_xor(s,  off);
    ss += __shfl_xor(ss, off);
  }
  const float mu  = s * (1.0f / 64.0f);
  const float var = ss * (1.0f / 64.0f) - mu * mu;
  const float inv = rsqrtf(var + 1e-5f);
  hout[(size_t)i * CH + lane] = (acc - mu) * inv * gamma[lane] + beta[lane];
}

// ---------------- Kernel B: MLP (64->256, exact GELU, 256->64) + residual ----
// 32 voxels per 256-thread block; LDS reads vectorized to ds_read_b128.
__global__ __launch_bounds__(256) void mlp_kernel(
    const float* __restrict__ h, const float* __restrict__ x,
    const float* __restrict__ W2, const float* __restrict__ b2,
    const float* __restrict__ W3, const float* __restrict__ b3,
    float* __restrict__ out, int N) {
  __shared__ float hs[32][CH];     // 8 KB
  __shared__ float gh[32][HIDD];   // 32 KB
  const int t = threadIdx.x;
  const long vbase = (long)blockIdx.x * 32;

  // cooperative load of the h tile (coalesced)
#pragma unroll
  for (int r = 0; r < 8; ++r) {
    int e = r * 256 + t;
    ((float*)hs)[e] = h[vbase * CH + e];
  }
  __syncthreads();

  // stage 1: thread t owns hidden unit j=t for all 32 voxels
  float w[CH];
#pragma unroll
  for (int c = 0; c < CH; ++c) w[c] = W2[c * HIDD + t];
  const float bb = b2[t];

  float acc[32];
  for (int v = 0; v < 32; ++v) {
    const float4* h4 = (const float4*)hs[v];
    float a = 0.f;
#pragma unroll
    for (int c4 = 0; c4 < CH / 4; ++c4) {
      float4 hv = h4[c4];                       // ds_read_b128 broadcast
      a += hv.x * w[4 * c4 + 0] + hv.y * w[4 * c4 + 1]
         + hv.z * w[4 * c4 + 2] + hv.w * w[4 * c4 + 3];
    }
    acc[v] = a + bb;
  }

  // exact GELU, stage into LDS
#pragma unroll
  for (int v = 0; v < 32; ++v) {
    float z = acc[v];
    gh[v][t] = 0.5f * z * (1.0f + erff(z * 0.70710678118654752f));
  }
  __syncthreads();

  // stage 2: lane c = t&63 -> out channel c; group vg = t>>6 covers 8 voxels
  const int c = t & 63, vg = t >> 6;
  float o[8];
#pragma unroll
  for (int vv = 0; vv < 8; ++vv) o[vv] = b3[c];
  for (int j4 = 0; j4 < HIDD / 4; ++j4) {
    const float w30 = W3[(4 * j4 + 0) * CH + c];   // coalesced, cache-resident
    const float w31 = W3[(4 * j4 + 1) * CH + c];
    const float w32 = W3[(4 * j4 + 2) * CH + c];
    const float w33 = W3[(4 * j4 + 3) * CH + c];
#pragma unroll
    for (int vv = 0; vv < 8; ++vv) {
      float4 gv = *(const float4*)&gh[vg * 8 + vv][4 * j4];  // b128 broadcast
      o[vv] += gv.x * w30 + gv.y * w31 + gv.z * w32 + gv.w * w33;
    }
  }
#pragma unroll
  for (int vv = 0; vv < 8; ++vv) {
    long v = vbase + vg * 8 + vv;
    if (v < N) out[v * CH + c] = o[vv] + x[v * CH + c];
  }
}

extern "C" void kernel_launch(void* const* d_in, const int* in_sizes, int n_in,
                              void* d_out, int out_size, void* d_ws, size_t ws_size,
                              hipStream_t stream) {
  const float* x_feat = (const float*)d_in[0];
  const int*   nbr    = (const int*)d_in[1];
  const float* W1     = (const float*)d_in[2];
  const float* b1     = (const float*)d_in[3];
  const float* gamma  = (const float*)d_in[4];
  const float* beta   = (const float*)d_in[5];
  const float* W2     = (const float*)d_in[6];
  const float* b2     = (const float*)d_in[7];
  const float* W3     = (const float*)d_in[8];
  const float* b3     = (const float*)d_in[9];
  float* out = (float*)d_out;

  const int N = in_sizes[0] / CH;      // 100000
  float* hbuf = (float*)d_ws;          // [N, CH] fp32 = 25.6 MB

  dim3 blkA(256);
  dim3 grdA((N + 3) / 4);
  hipLaunchKernelGGL(dw_gn_kernel, grdA, blkA, 0, stream,
                     x_feat, nbr, W1, b1, gamma, beta, hbuf, N);

  dim3 blkB(256);
  dim3 grdB((N + 31) / 32);
  hipLaunchKernelGGL(mlp_kernel, grdB, blkB, 0, stream,
                     hbuf, x_feat, W2, b2, W3, b3, out, N);
}

// Round 5
// 583.309 us; speedup vs baseline: 3.5013x; 1.2325x over previous
//
#include <hip/hip_runtime.h>
#include <hip/hip_bf16.h>
#include <math.h>

#define CH    64
#define KT    343
#define HIDD  256

typedef __attribute__((ext_vector_type(8))) short short8;
typedef __attribute__((ext_vector_type(4))) float f32x4;

// ---------------- Kernel P: weight transpose + bf16 cast ----------------
__global__ __launch_bounds__(256) void prep_kernel(
    const float* __restrict__ W2, const float* __restrict__ W3,
    __hip_bfloat16* __restrict__ W2T, __hip_bfloat16* __restrict__ W3T) {
  const int t = blockIdx.x * 256 + threadIdx.x;
  const int step = gridDim.x * 256;
  // W2 [64,256] -> W2T [256,64]
  for (int e = t; e < CH * HIDD; e += step) {
    int k = e >> 8, n = e & 255;
    W2T[n * CH + k] = __float2bfloat16(W2[e]);
  }
  // W3 [256,64] -> W3T [64,256]
  for (int e = t; e < HIDD * CH; e += step) {
    int k = e >> 6, n = e & 63;
    W3T[n * HIDD + k] = __float2bfloat16(W3[e]);
  }
}

// ---------------- Kernel A: depthwise gather conv + GroupNorm (bf16 out) ----
__global__ __launch_bounds__(256) void dw_gn_kernel(
    const float* __restrict__ x, const int* __restrict__ nbr,
    const float* __restrict__ W1, const float* __restrict__ b1,
    const float* __restrict__ gamma, const float* __restrict__ beta,
    __hip_bfloat16* __restrict__ hout, int N) {
  const int lane = threadIdx.x & 63;
  const int i = __builtin_amdgcn_readfirstlane(blockIdx.x * 4 + (threadIdx.x >> 6));
  if (i >= N) return;

  const int* nb = nbr + (size_t)i * KT;   // uniform pointer -> SGPR base
  float acc = 0.f;

  for (int k = 0; k < 336; k += 16) {
    int idx[16];
#pragma unroll
    for (int j = 0; j < 16; ++j) idx[j] = nb[k + j];

    float g[16], w[16];
    const float* wb = W1 + k * CH;
#pragma unroll
    for (int j = 0; j < 16; ++j) {
      if (idx[j] < N) {                    // scalar branch (idx is SGPR)
        const float* p = x + ((size_t)(unsigned)idx[j] << 6);
        g[j] = p[lane];
        w[j] = wb[j * CH + lane];
      } else {
        g[j] = 0.f;
        w[j] = 0.f;
      }
    }
#pragma unroll
    for (int j = 0; j < 16; ++j) acc = fmaf(g[j], w[j], acc);
  }
  {
    int idx[7];
#pragma unroll
    for (int j = 0; j < 7; ++j) idx[j] = nb[336 + j];
    float g[7], w[7];
    const float* wb = W1 + 336 * CH;
#pragma unroll
    for (int j = 0; j < 7; ++j) {
      if (idx[j] < N) {
        const float* p = x + ((size_t)(unsigned)idx[j] << 6);
        g[j] = p[lane];
        w[j] = wb[j * CH + lane];
      } else {
        g[j] = 0.f;
        w[j] = 0.f;
      }
    }
#pragma unroll
    for (int j = 0; j < 7; ++j) acc = fmaf(g[j], w[j], acc);
  }

  acc += b1[lane];

  float s = acc, ss = acc * acc;
#pragma unroll
  for (int off = 32; off > 0; off >>= 1) {
    s  += __shfl_xor(s,  off);
    ss += __shfl_xor(ss, off);
  }
  const float mu  = s * (1.0f / 64.0f);
  const float var = ss * (1.0f / 64.0f) - mu * mu;
  const float inv = rsqrtf(var + 1e-5f);
  hout[(size_t)i * CH + lane] =
      __float2bfloat16((acc - mu) * inv * gamma[lane] + beta[lane]);
}

// ---------------- Kernel B: MFMA MLP + GELU + residual ----------------
// 32 voxels per 256-thread block (4 waves). bf16 MFMA 16x16x32.
// GEMM1: [32,64]x[64,256]; wave w owns hidden cols [w*64, w*64+64).
// GELU -> bf16 LDS (C-layout -> A-layout round trip).
// GEMM2: [32,256]x[256,64]; wave w owns out cols [w*16, w*16+16).
__global__ __launch_bounds__(256) void mlp_mfma_kernel(
    const __hip_bfloat16* __restrict__ h, const float* __restrict__ x,
    const __hip_bfloat16* __restrict__ W2T, const float* __restrict__ b2,
    const __hip_bfloat16* __restrict__ W3T, const float* __restrict__ b3,
    float* __restrict__ out, int N) {
  __shared__ short hs[32][CH + 8];      // 4.5 KB, pad 8 -> bank rotation
  __shared__ short gs[32][HIDD + 8];    // 16.5 KB

  const int t = threadIdx.x;
  const int wv = t >> 6;
  const int lane = t & 63;
  const int row16 = lane & 15;
  const int quad = lane >> 4;
  const int vbase = blockIdx.x * 32;    // N divisible by 32

  // stage h tile [32][64] bf16: thread t -> 8 contiguous elements
  {
    const int r = t >> 3, c = (t & 7) * 8;
    short8 v = *(const short8*)((const short*)h + (size_t)(vbase + r) * CH + c);
    *(short8*)&hs[r][c] = v;
  }
  __syncthreads();

  // ---- GEMM1 ----
  short8 afr[2][2];
#pragma unroll
  for (int rt = 0; rt < 2; ++rt)
#pragma unroll
    for (int ks = 0; ks < 2; ++ks)
      afr[rt][ks] = *(short8*)&hs[rt * 16 + row16][ks * 32 + quad * 8];

  f32x4 acc[2][4];
#pragma unroll
  for (int rt = 0; rt < 2; ++rt)
#pragma unroll
    for (int cl = 0; cl < 4; ++cl) acc[rt][cl] = (f32x4){0.f, 0.f, 0.f, 0.f};

#pragma unroll
  for (int cl = 0; cl < 4; ++cl) {
    const int n = wv * 64 + cl * 16 + row16;
#pragma unroll
    for (int ks = 0; ks < 2; ++ks) {
      short8 bfr = *(const short8*)((const short*)W2T + (size_t)n * CH + ks * 32 + quad * 8);
#pragma unroll
      for (int rt = 0; rt < 2; ++rt)
        acc[rt][cl] = __builtin_amdgcn_mfma_f32_16x16x32_bf16(afr[rt][ks], bfr, acc[rt][cl], 0, 0, 0);
    }
  }

  // bias + exact GELU -> gs (bf16)
#pragma unroll
  for (int cl = 0; cl < 4; ++cl) {
    const int n = wv * 64 + cl * 16 + row16;
    const float bias = b2[n];
#pragma unroll
    for (int rt = 0; rt < 2; ++rt) {
#pragma unroll
      for (int r = 0; r < 4; ++r) {
        float z = acc[rt][cl][r] + bias;
        float ge = 0.5f * z * (1.0f + erff(z * 0.70710678118654752f));
        gs[rt * 16 + quad * 4 + r][n] = (short)__bfloat16_as_ushort(__float2bfloat16(ge));
      }
    }
  }
  __syncthreads();

  // ---- GEMM2 ----
  f32x4 oacc[2];
  oacc[0] = (f32x4){0.f, 0.f, 0.f, 0.f};
  oacc[1] = (f32x4){0.f, 0.f, 0.f, 0.f};
  const int oc = wv * 16 + row16;       // out channel for this lane
#pragma unroll
  for (int ks = 0; ks < 8; ++ks) {
    short8 bfr = *(const short8*)((const short*)W3T + (size_t)oc * HIDD + ks * 32 + quad * 8);
#pragma unroll
    for (int rt = 0; rt < 2; ++rt) {
      short8 a2 = *(short8*)&gs[rt * 16 + row16][ks * 32 + quad * 8];
      oacc[rt] = __builtin_amdgcn_mfma_f32_16x16x32_bf16(a2, bfr, oacc[rt], 0, 0, 0);
    }
  }

  // epilogue: bias + residual + store (C layout: row=quad*4+r, col=oc)
  const float bias3 = b3[oc];
#pragma unroll
  for (int rt = 0; rt < 2; ++rt) {
#pragma unroll
    for (int r = 0; r < 4; ++r) {
      const size_t vrow = (size_t)vbase + rt * 16 + quad * 4 + r;
      out[vrow * CH + oc] = oacc[rt][r] + bias3 + x[vrow * CH + oc];
    }
  }
}

extern "C" void kernel_launch(void* const* d_in, const int* in_sizes, int n_in,
                              void* d_out, int out_size, void* d_ws, size_t ws_size,
                              hipStream_t stream) {
  const float* x_feat = (const float*)d_in[0];
  const int*   nbr    = (const int*)d_in[1];
  const float* W1     = (const float*)d_in[2];
  const float* b1     = (const float*)d_in[3];
  const float* gamma  = (const float*)d_in[4];
  const float* beta   = (const float*)d_in[5];
  const float* W2     = (const float*)d_in[6];
  const float* b2     = (const float*)d_in[7];
  const float* W3     = (const float*)d_in[8];
  const float* b3     = (const float*)d_in[9];
  float* out = (float*)d_out;

  const int N = in_sizes[0] / CH;      // 100000

  char* ws = (char*)d_ws;
  __hip_bfloat16* hbuf = (__hip_bfloat16*)ws;                       // 12.8 MB
  __hip_bfloat16* W2T  = (__hip_bfloat16*)(ws + (size_t)N * CH * 2);          // 32 KB
  __hip_bfloat16* W3T  = (__hip_bfloat16*)(ws + (size_t)N * CH * 2 + 32768);  // 32 KB

  hipLaunchKernelGGL(prep_kernel, dim3(64), dim3(256), 0, stream, W2, W3, W2T, W3T);

  hipLaunchKernelGGL(dw_gn_kernel, dim3((N + 3) / 4), dim3(256), 0, stream,
                     x_feat, nbr, W1, b1, gamma, beta, hbuf, N);

  hipLaunchKernelGGL(mlp_mfma_kernel, dim3(N / 32), dim3(256), 0, stream,
                     hbuf, x_feat, W2T, b2, W3T, b3, out, N);
}

// Round 6
// 562.317 us; speedup vs baseline: 3.6320x; 1.0373x over previous
//
#include <hip/hip_runtime.h>
#include <hip/hip_fp16.h>
#include <math.h>

#define CH    64
#define KT    343
#define HIDD  256

typedef __attribute__((ext_vector_type(8))) _Float16 half8;
typedef __attribute__((ext_vector_type(4))) _Float16 half4;
typedef __attribute__((ext_vector_type(4))) float f32x4;
struct H24 { __half2 x, y, z, w; };

// ---------------- Kernel P1: weight casts/transposes (f16) ----------------
__global__ __launch_bounds__(256) void prep_w_kernel(
    const float* __restrict__ W1, const float* __restrict__ W2,
    const float* __restrict__ W3, _Float16* __restrict__ W1h,
    _Float16* __restrict__ W2Th, _Float16* __restrict__ W3Th) {
  const int t = blockIdx.x * 256 + threadIdx.x;
  const int step = gridDim.x * 256;
  for (int e = t; e < KT * CH; e += step) W1h[e] = (_Float16)W1[e];
  // W2 [64,256] -> W2Th [256,64]
  for (int e = t; e < CH * HIDD; e += step) {
    int k = e >> 8, n = e & 255;
    W2Th[n * CH + k] = (_Float16)W2[e];
  }
  // W3 [256,64] -> W3Th [64,256]
  for (int e = t; e < HIDD * CH; e += step) {
    int k = e >> 6, n = e & 63;
    W3Th[n * HIDD + k] = (_Float16)W3[e];
  }
}

// ---------------- Kernel P2: x -> f16, plus one zero row at index N --------
__global__ __launch_bounds__(256) void xcast_kernel(
    const float* __restrict__ x, _Float16* __restrict__ xh, int nelem) {
  const int tot4 = nelem / 4 + 16;     // includes the 64-elem zero pad row
  for (int q = blockIdx.x * 256 + threadIdx.x; q < tot4; q += gridDim.x * 256) {
    const int eb = q * 4;
    float4 v = (eb < nelem) ? *(const float4*)(x + eb) : make_float4(0.f, 0.f, 0.f, 0.f);
    half4 o;
    o[0] = (_Float16)v.x; o[1] = (_Float16)v.y;
    o[2] = (_Float16)v.z; o[3] = (_Float16)v.w;
    *(half4*)(xh + eb) = o;
  }
}

// ---------------- Fused: depthwise conv + GN + MFMA MLP + residual ---------
// 256 threads = 4 waves; each wave handles 8 voxels in the conv phase
// (8 lanes/voxel, 8 f16 channels/lane), so the block covers the 32-voxel
// MLP tile exactly. Invalid taps (idx==N) read the zero row of xh.
__global__ __launch_bounds__(256) void fused_kernel(
    const _Float16* __restrict__ xh, const float* __restrict__ x,
    const int* __restrict__ nbr, const _Float16* __restrict__ W1h,
    const float* __restrict__ b1, const float* __restrict__ gamma,
    const float* __restrict__ beta, const _Float16* __restrict__ W2Th,
    const float* __restrict__ b2, const _Float16* __restrict__ W3Th,
    const float* __restrict__ b3, float* __restrict__ out, int N) {
  __shared__ __align__(16) _Float16 hs[32][CH + 8];     // 4.6 KB
  __shared__ __align__(16) _Float16 gs[32][HIDD + 8];   // 16.9 KB

  const int t = threadIdx.x;
  const int wv = t >> 6;
  const int lane = t & 63;
  const int g = lane >> 3;           // voxel within wave's group of 8
  const int e = lane & 7;            // channel oct: channels e*8 .. e*8+7
  const int e16 = e << 4;            // byte offset within a 128B f16 row
  const int pb = (lane & 56) << 2;   // ds_bpermute base: lane-group start *4
  const int vbase = blockIdx.x * 32;
  const int vb = __builtin_amdgcn_readfirstlane(vbase + wv * 8);

  // ---- phase 1: depthwise gather conv, f16 packed MACs ----
  const int* nbw = nbr + (size_t)vb * KT;
  const int nbo = g * KT + e;        // this lane streams taps e, e+8, e+16...

  __half2 acc0 = __float2half2_rn(0.f), acc1 = acc0, acc2 = acc0, acc3 = acc0;
  const char* xb = (const char*)xh;
  const char* wb = (const char*)W1h;

  for (int ck = 0; ck < 42; ++ck) {
    const int vi = nbw[nbo + ck * 8];    // 8 taps x 8 voxels in one load
    const char* wp = wb + ck * 1024;
#pragma unroll
    for (int j = 0; j < 8; ++j) {
      const int idx = __builtin_amdgcn_ds_bpermute(pb + 4 * j, vi);
      const unsigned off = ((unsigned)idx << 7) + (unsigned)e16;
      const uint4 gv = *(const uint4*)(xb + off);          // 8 ch gather
      const uint4 wv4 = *(const uint4*)(wp + j * 128 + e16);
      const H24 gh = __builtin_bit_cast(H24, gv);
      const H24 wh = __builtin_bit_cast(H24, wv4);
      acc0 = __hfma2(gh.x, wh.x, acc0);
      acc1 = __hfma2(gh.y, wh.y, acc1);
      acc2 = __hfma2(gh.z, wh.z, acc2);
      acc3 = __hfma2(gh.w, wh.w, acc3);
    }
  }
  {  // tail: taps 336..342 (vi holds taps 335..342; skip j=0)
    const int vi = nbw[nbo + 335];
    const char* wp = wb + 335 * 128;
#pragma unroll
    for (int j = 1; j < 8; ++j) {
      const int idx = __builtin_amdgcn_ds_bpermute(pb + 4 * j, vi);
      const unsigned off = ((unsigned)idx << 7) + (unsigned)e16;
      const uint4 gv = *(const uint4*)(xb + off);
      const uint4 wv4 = *(const uint4*)(wp + j * 128 + e16);
      const H24 gh = __builtin_bit_cast(H24, gv);
      const H24 wh = __builtin_bit_cast(H24, wv4);
      acc0 = __hfma2(gh.x, wh.x, acc0);
      acc1 = __hfma2(gh.y, wh.y, acc1);
      acc2 = __hfma2(gh.z, wh.z, acc2);
      acc3 = __hfma2(gh.w, wh.w, acc3);
    }
  }

  // ---- phase 2: bias + GroupNorm over the 8-lane voxel group ----
  float fa[8];
  fa[0] = __low2float(acc0); fa[1] = __high2float(acc0);
  fa[2] = __low2float(acc1); fa[3] = __high2float(acc1);
  fa[4] = __low2float(acc2); fa[5] = __high2float(acc2);
  fa[6] = __low2float(acc3); fa[7] = __high2float(acc3);
  {
    float4 blo = *(const float4*)(b1 + e * 8);
    float4 bhi = *(const float4*)(b1 + e * 8 + 4);
    fa[0] += blo.x; fa[1] += blo.y; fa[2] += blo.z; fa[3] += blo.w;
    fa[4] += bhi.x; fa[5] += bhi.y; fa[6] += bhi.z; fa[7] += bhi.w;
  }
  float s = 0.f, ss = 0.f;
#pragma unroll
  for (int d = 0; d < 8; ++d) { s += fa[d]; ss += fa[d] * fa[d]; }
  s += __shfl_xor(s, 1); ss += __shfl_xor(ss, 1);
  s += __shfl_xor(s, 2); ss += __shfl_xor(ss, 2);
  s += __shfl_xor(s, 4); ss += __shfl_xor(ss, 4);
  const float mu = s * (1.0f / 64.0f);
  const float var = ss * (1.0f / 64.0f) - mu * mu;
  const float inv = rsqrtf(var + 1e-5f);
  {
    float4 glo = *(const float4*)(gamma + e * 8);
    float4 ghi = *(const float4*)(gamma + e * 8 + 4);
    float4 tlo = *(const float4*)(beta + e * 8);
    float4 thi = *(const float4*)(beta + e * 8 + 4);
    const float gm[8] = {glo.x, glo.y, glo.z, glo.w, ghi.x, ghi.y, ghi.z, ghi.w};
    const float bt[8] = {tlo.x, tlo.y, tlo.z, tlo.w, thi.x, thi.y, thi.z, thi.w};
    half8 hv;
#pragma unroll
    for (int d = 0; d < 8; ++d)
      hv[d] = (_Float16)((fa[d] - mu) * inv * gm[d] + bt[d]);
    *(half8*)&hs[wv * 8 + g][e * 8] = hv;
  }
  __syncthreads();

  // ---- phase 3: GEMM1 [32,64]x[64,256] + GELU -> gs ----
  const int row16 = lane & 15, quad = lane >> 4;
  half8 afr[2][2];
#pragma unroll
  for (int rt = 0; rt < 2; ++rt)
#pragma unroll
    for (int ks = 0; ks < 2; ++ks)
      afr[rt][ks] = *(const half8*)&hs[rt * 16 + row16][ks * 32 + quad * 8];

#pragma unroll
  for (int cl = 0; cl < 4; ++cl) {
    const int n = wv * 64 + cl * 16 + row16;
    f32x4 a0 = {0.f, 0.f, 0.f, 0.f}, a1 = {0.f, 0.f, 0.f, 0.f};
#pragma unroll
    for (int ks = 0; ks < 2; ++ks) {
      half8 bfr = *(const half8*)(W2Th + (size_t)n * CH + ks * 32 + quad * 8);
      a0 = __builtin_amdgcn_mfma_f32_16x16x32_f16(afr[0][ks], bfr, a0, 0, 0, 0);
      a1 = __builtin_amdgcn_mfma_f32_16x16x32_f16(afr[1][ks], bfr, a1, 0, 0, 0);
    }
    const float bias = b2[n];
#pragma unroll
    for (int r = 0; r < 4; ++r) {
      float z0 = a0[r] + bias;
      float z1 = a1[r] + bias;
      gs[quad * 4 + r][n]      = (_Float16)(0.5f * z0 * (1.0f + erff(z0 * 0.70710678118654752f)));
      gs[16 + quad * 4 + r][n] = (_Float16)(0.5f * z1 * (1.0f + erff(z1 * 0.70710678118654752f)));
    }
  }
  __syncthreads();

  // ---- phase 4: GEMM2 [32,256]x[256,64] + bias + residual ----
  f32x4 o0 = {0.f, 0.f, 0.f, 0.f}, o1 = {0.f, 0.f, 0.f, 0.f};
  const int oc = wv * 16 + row16;
#pragma unroll
  for (int ks = 0; ks < 8; ++ks) {
    half8 bfr = *(const half8*)(W3Th + (size_t)oc * HIDD + ks * 32 + quad * 8);
    half8 a20 = *(const half8*)&gs[row16][ks * 32 + quad * 8];
    half8 a21 = *(const half8*)&gs[16 + row16][ks * 32 + quad * 8];
    o0 = __builtin_amdgcn_mfma_f32_16x16x32_f16(a20, bfr, o0, 0, 0, 0);
    o1 = __builtin_amdgcn_mfma_f32_16x16x32_f16(a21, bfr, o1, 0, 0, 0);
  }
  const float bias3 = b3[oc];
#pragma unroll
  for (int r = 0; r < 4; ++r) {
    size_t v0 = (size_t)vbase + quad * 4 + r;
    size_t v1 = (size_t)vbase + 16 + quad * 4 + r;
    out[v0 * CH + oc] = o0[r] + bias3 + x[v0 * CH + oc];
    out[v1 * CH + oc] = o1[r] + bias3 + x[v1 * CH + oc];
  }
}

extern "C" void kernel_launch(void* const* d_in, const int* in_sizes, int n_in,
                              void* d_out, int out_size, void* d_ws, size_t ws_size,
                              hipStream_t stream) {
  const float* x_feat = (const float*)d_in[0];
  const int*   nbr    = (const int*)d_in[1];
  const float* W1     = (const float*)d_in[2];
  const float* b1     = (const float*)d_in[3];
  const float* gamma  = (const float*)d_in[4];
  const float* beta   = (const float*)d_in[5];
  const float* W2     = (const float*)d_in[6];
  const float* b2     = (const float*)d_in[7];
  const float* W3     = (const float*)d_in[8];
  const float* b3     = (const float*)d_in[9];
  float* out = (float*)d_out;

  const int N = in_sizes[0] / CH;      // 100000 (divisible by 32)

  char* ws = (char*)d_ws;
  size_t off = 0;
  _Float16* xh = (_Float16*)(ws + off);
  off += (((size_t)(N + 1) * CH * 2) + 255) & ~(size_t)255;   // x f16 + zero row
  _Float16* W1h = (_Float16*)(ws + off);
  off += ((size_t)KT * CH * 2 + 255) & ~(size_t)255;
  _Float16* W2Th = (_Float16*)(ws + off);
  off += ((size_t)HIDD * CH * 2 + 255) & ~(size_t)255;
  _Float16* W3Th = (_Float16*)(ws + off);

  hipLaunchKernelGGL(prep_w_kernel, dim3(32), dim3(256), 0, stream,
                     W1, W2, W3, W1h, W2Th, W3Th);
  hipLaunchKernelGGL(xcast_kernel, dim3(1024), dim3(256), 0, stream,
                     x_feat, xh, N * CH);
  hipLaunchKernelGGL(fused_kernel, dim3(N / 32), dim3(256), 0, stream,
                     xh, x_feat, nbr, W1h, b1, gamma, beta,
                     W2Th, b2, W3Th, b3, out, N);
}